// Round 1
// 2295.654 us; speedup vs baseline: 1.4116x; 1.4116x over previous
//
#include <hip/hip_runtime.h>
#include <cmath>

typedef _Float16 half_t;
typedef unsigned short ushort_t;
typedef __attribute__((ext_vector_type(8))) _Float16 half8;
typedef __attribute__((ext_vector_type(4))) _Float16 half4v;
typedef __attribute__((ext_vector_type(8))) short short8;
typedef __attribute__((ext_vector_type(4))) float f32x4;

#define T_TOK   9216
#define DIN     1024
#define DMOD    2048
#define HDIM    8192
#define NEXP    4
#define CAPN    3456          // int(1.5 * 9216 / 4)
#define GAP_TAU 5e-5          // top-2 gap below which we recompute logits in fp64

__device__ inline float geluf(float x) {
    return 0.5f * x * (1.0f + erff(x * 0.70710678118654752440f));
}
__device__ inline double gelud(double x) {
    return 0.5 * x * (1.0 + erf(x * 0.70710678118654752440));
}
__device__ inline double waveRedD(double v) {
#pragma unroll
    for (int off = 32; off; off >>= 1) v += __shfl_down(v, off);
    return v;
}
__device__ inline ushort_t bf16rn(float f) {
    unsigned u = __float_as_uint(f);
    unsigned r = (u + 0x7FFFu + ((u >> 16) & 1u)) >> 16;
    return (ushort_t)r;
}
__device__ inline float bf16tof(ushort_t h) {
    return __uint_as_float(((unsigned)h) << 16);
}
// async global->LDS, 16 bytes/lane. LDS dest must be wave-uniform base + lane*16.
__device__ __forceinline__ void gld16(const void* g, void* l) {
    __builtin_amdgcn_global_load_lds((const __attribute__((address_space(1))) void*)g,
                                     (__attribute__((address_space(3))) void*)l, 16, 0, 0);
}

// ---------------------------------------------------------------- K1: LayerNorm (fp64 stats) -> bf16 hi/lo split
__global__ __launch_bounds__(256) void k1_ln(const float* __restrict__ x,
                                             const float* __restrict__ g,
                                             const float* __restrict__ b,
                                             ushort_t* __restrict__ xh,
                                             ushort_t* __restrict__ xl) {
    const int row = blockIdx.x;
    const int tid = threadIdx.x;
    const int c = tid * 4;
    const float4 v = *(const float4*)&x[(size_t)row * DIN + c];
    __shared__ double sw[8];
    __shared__ double bc[2];
    const int lane = tid & 63, wv = tid >> 6;

    double s = (double)v.x + (double)v.y + (double)v.z + (double)v.w;
    s = waveRedD(s);
    if (lane == 0) sw[wv] = s;
    __syncthreads();
    if (tid == 0) bc[0] = (sw[0] + sw[1] + sw[2] + sw[3]) * (1.0 / 1024.0);
    __syncthreads();
    const double mu = bc[0];
    const double d0 = (double)v.x - mu, d1 = (double)v.y - mu;
    const double d2 = (double)v.z - mu, d3 = (double)v.w - mu;
    double s2 = d0 * d0 + d1 * d1 + d2 * d2 + d3 * d3;
    s2 = waveRedD(s2);
    if (lane == 0) sw[4 + wv] = s2;
    __syncthreads();
    if (tid == 0) bc[1] = 1.0 / sqrt((sw[4] + sw[5] + sw[6] + sw[7]) * (1.0 / 1024.0) + 1e-5);
    __syncthreads();
    const double rs = bc[1];
    const float4 gv = *(const float4*)&g[c];
    const float4 bv = *(const float4*)&b[c];
    float o0 = (float)(d0 * rs * (double)gv.x + (double)bv.x);
    float o1 = (float)(d1 * rs * (double)gv.y + (double)bv.y);
    float o2 = (float)(d2 * rs * (double)gv.z + (double)bv.z);
    float o3 = (float)(d3 * rs * (double)gv.w + (double)bv.w);
    ushort4 hv, lv;
    hv.x = bf16rn(o0); lv.x = bf16rn(o0 - bf16tof(hv.x));
    hv.y = bf16rn(o1); lv.y = bf16rn(o1 - bf16tof(hv.y));
    hv.z = bf16rn(o2); lv.z = bf16rn(o2 - bf16tof(hv.z));
    hv.w = bf16rn(o3); lv.w = bf16rn(o3 - bf16tof(hv.w));
    *(ushort4*)&xh[(size_t)row * DIN + c] = hv;
    *(ushort4*)&xl[(size_t)row * DIN + c] = lv;
}

// ---------------------------------------------------------------- KT1: fp32 [K][N] -> bf16 hi/lo transposed [N][K]
#define TT_ST 68
__global__ __launch_bounds__(256) void kt_bf16x2(const float* __restrict__ src,
                                                 ushort_t* __restrict__ dhi,
                                                 ushort_t* __restrict__ dlo,
                                                 int K, int N) {
    __shared__ ushort_t th[64 * TT_ST];
    __shared__ ushort_t tl[64 * TT_ST];
    const int n0 = blockIdx.x * 64, k0 = blockIdx.y * 64;
    const int t = threadIdx.x, tr = t >> 4, tc = (t & 15) * 4;
#pragma unroll
    for (int r = 0; r < 4; ++r) {
        const int row = r * 16 + tr;
        const float4 v = *(const float4*)&src[(size_t)(k0 + row) * N + n0 + tc];
        const float vv[4] = {v.x, v.y, v.z, v.w};
#pragma unroll
        for (int j = 0; j < 4; ++j) {
            const ushort_t h = bf16rn(vv[j]);
            th[(tc + j) * TT_ST + row] = h;
            tl[(tc + j) * TT_ST + row] = bf16rn(vv[j] - bf16tof(h));
        }
    }
    __syncthreads();
#pragma unroll
    for (int r = 0; r < 4; ++r) {
        const int row = r * 16 + tr;
        ushort4 hv, lv;
        hv.x = th[row * TT_ST + tc + 0]; lv.x = tl[row * TT_ST + tc + 0];
        hv.y = th[row * TT_ST + tc + 1]; lv.y = tl[row * TT_ST + tc + 1];
        hv.z = th[row * TT_ST + tc + 2]; lv.z = tl[row * TT_ST + tc + 2];
        hv.w = th[row * TT_ST + tc + 3]; lv.w = tl[row * TT_ST + tc + 3];
        *(ushort4*)&dhi[(size_t)(n0 + row) * K + k0 + tc] = hv;
        *(ushort4*)&dlo[(size_t)(n0 + row) * K + k0 + tc] = lv;
    }
}

// ---------------------------------------------------------------- KT2: fp32 [K][N] -> fp16 transposed [N][K]
__global__ __launch_bounds__(256) void kt_f16(const float* __restrict__ src,
                                              half_t* __restrict__ dst,
                                              int K, int N) {
    __shared__ half_t tile[64 * TT_ST];
    const int n0 = blockIdx.x * 64, k0 = blockIdx.y * 64;
    const int t = threadIdx.x, tr = t >> 4, tc = (t & 15) * 4;
#pragma unroll
    for (int r = 0; r < 4; ++r) {
        const int row = r * 16 + tr;
        const float4 v = *(const float4*)&src[(size_t)(k0 + row) * N + n0 + tc];
        tile[(tc + 0) * TT_ST + row] = (half_t)v.x;
        tile[(tc + 1) * TT_ST + row] = (half_t)v.y;
        tile[(tc + 2) * TT_ST + row] = (half_t)v.z;
        tile[(tc + 3) * TT_ST + row] = (half_t)v.w;
    }
    __syncthreads();
#pragma unroll
    for (int r = 0; r < 4; ++r) {
        const int row = r * 16 + tr;
        const half4v v4 = *(const half4v*)&tile[row * TT_ST + tc];
        *(half4v*)&dst[(size_t)(n0 + row) * K + k0 + tc] = v4;
    }
}

// ---------------------------------------------------------------- K2: pre_linear bf16x3 MFMA GEMM + GELU
// C = (Ah+Al)(Bh+Bl) ~= Ah*Bh + Ah*Bl + Al*Bh  (error ~2^-16 rel, << GAP_TAU budget)
__global__ __launch_bounds__(256) void k2_pre(const ushort_t* __restrict__ xh,
                                              const ushort_t* __restrict__ xl,
                                              const ushort_t* __restrict__ wh,
                                              const ushort_t* __restrict__ wl,
                                              const float* __restrict__ bias,
                                              float* __restrict__ t32,
                                              half_t* __restrict__ t16) {
    __shared__ ushort_t Ah[128 * 32];
    __shared__ ushort_t Al[128 * 32];
    __shared__ ushort_t Bh[128 * 32];
    __shared__ ushort_t Bl[128 * 32];
    const int tid = threadIdx.x;
    const int m0 = blockIdx.y * 128, n0 = blockIdx.x * 128;
    const int r4 = tid >> 2, sg = (tid & 3) * 8;
    const ushort_t* gah0 = xh + (size_t)(m0 + r4) * DIN + sg;
    const ushort_t* gah1 = xh + (size_t)(m0 + 64 + r4) * DIN + sg;
    const ushort_t* gal0 = xl + (size_t)(m0 + r4) * DIN + sg;
    const ushort_t* gal1 = xl + (size_t)(m0 + 64 + r4) * DIN + sg;
    const ushort_t* gbh0 = wh + (size_t)(n0 + r4) * DIN + sg;
    const ushort_t* gbh1 = wh + (size_t)(n0 + 64 + r4) * DIN + sg;
    const ushort_t* gbl0 = wl + (size_t)(n0 + r4) * DIN + sg;
    const ushort_t* gbl1 = wl + (size_t)(n0 + 64 + r4) * DIN + sg;
    ushort_t* lAh0 = &Ah[tid * 8]; ushort_t* lAh1 = &Ah[2048 + tid * 8];
    ushort_t* lAl0 = &Al[tid * 8]; ushort_t* lAl1 = &Al[2048 + tid * 8];
    ushort_t* lBh0 = &Bh[tid * 8]; ushort_t* lBh1 = &Bh[2048 + tid * 8];
    ushort_t* lBl0 = &Bl[tid * 8]; ushort_t* lBl1 = &Bl[2048 + tid * 8];
    const int w = tid >> 6, lane = tid & 63, q = lane >> 4, mr = lane & 15;
    const int wm = (w & 1) * 64, wn = (w >> 1) * 64;

    f32x4 acc[4][4];
#pragma unroll
    for (int i = 0; i < 4; ++i)
#pragma unroll
        for (int j = 0; j < 4; ++j) acc[i][j] = (f32x4){0.f, 0.f, 0.f, 0.f};

    for (int k0 = 0; k0 < DIN; k0 += 32) {
        gld16(gah0 + k0, lAh0); gld16(gah1 + k0, lAh1);
        gld16(gal0 + k0, lAl0); gld16(gal1 + k0, lAl1);
        gld16(gbh0 + k0, lBh0); gld16(gbh1 + k0, lBh1);
        gld16(gbl0 + k0, lBl0); gld16(gbl1 + k0, lBl1);
        __syncthreads();
        short8 ah[4], al4[4], bh[4], bl4[4];
#pragma unroll
        for (int i = 0; i < 4; ++i) {
            ah[i]  = *(const short8*)&Ah[(wm + i * 16 + mr) * 32 + q * 8];
            al4[i] = *(const short8*)&Al[(wm + i * 16 + mr) * 32 + q * 8];
            bh[i]  = *(const short8*)&Bh[(wn + i * 16 + mr) * 32 + q * 8];
            bl4[i] = *(const short8*)&Bl[(wn + i * 16 + mr) * 32 + q * 8];
        }
#pragma unroll
        for (int i = 0; i < 4; ++i)
#pragma unroll
            for (int j = 0; j < 4; ++j) {
                acc[i][j] = __builtin_amdgcn_mfma_f32_16x16x32_bf16(al4[i], bh[j], acc[i][j], 0, 0, 0);
                acc[i][j] = __builtin_amdgcn_mfma_f32_16x16x32_bf16(ah[i], bl4[j], acc[i][j], 0, 0, 0);
                acc[i][j] = __builtin_amdgcn_mfma_f32_16x16x32_bf16(ah[i], bh[j], acc[i][j], 0, 0, 0);
            }
        __syncthreads();
    }
    float bb[4];
#pragma unroll
    for (int j = 0; j < 4; ++j) bb[j] = bias[n0 + wn + j * 16 + mr];
#pragma unroll
    for (int i = 0; i < 4; ++i) {
#pragma unroll
        for (int p = 0; p < 4; ++p) {
            const int row = m0 + wm + i * 16 + q * 4 + p;
#pragma unroll
            for (int j = 0; j < 4; ++j) {
                const int col = n0 + wn + j * 16 + mr;
                const float t = geluf(acc[i][j][p] + bb[j]);
                t32[(size_t)row * DMOD + col] = t;
                t16[(size_t)row * DMOD + col] = (half_t)t;
            }
        }
    }
}

// ---------------------------------------------------------------- K3: router logits (fp64 from fp32 t) + gap flags
__global__ __launch_bounds__(256) void k3_router(const float* __restrict__ t32,
                                                 const float* __restrict__ swW,
                                                 const float* __restrict__ swb,
                                                 double* __restrict__ logitsD,
                                                 int* __restrict__ flags) {
    const int tok = blockIdx.x * 4 + (threadIdx.x >> 6);
    const int lane = threadIdx.x & 63;
    const float* tr = t32 + (size_t)tok * DMOD;
    double a0 = 0, a1 = 0, a2 = 0, a3 = 0;
    for (int it = 0; it < 8; ++it) {
        const int k = it * 256 + lane * 4;
        const float4 tv = *(const float4*)&tr[k];
        const float tp[4] = {tv.x, tv.y, tv.z, tv.w};
#pragma unroll
        for (int j = 0; j < 4; ++j) {
            const float4 wv = *(const float4*)&swW[(size_t)(k + j) * 4];
            const double td = (double)tp[j];
            a0 += td * (double)wv.x;
            a1 += td * (double)wv.y;
            a2 += td * (double)wv.z;
            a3 += td * (double)wv.w;
        }
    }
    a0 = waveRedD(a0); a1 = waveRedD(a1); a2 = waveRedD(a2); a3 = waveRedD(a3);
    if (lane == 0) {
        a0 += (double)swb[0]; a1 += (double)swb[1]; a2 += (double)swb[2]; a3 += (double)swb[3];
        double* Lp = logitsD + (size_t)tok * 4;
        Lp[0] = a0; Lp[1] = a1; Lp[2] = a2; Lp[3] = a3;
        double m1 = a0, m2 = -1e300;
        if (a1 > m1) { m2 = m1; m1 = a1; } else if (a1 > m2) m2 = a1;
        if (a2 > m1) { m2 = m1; m1 = a2; } else if (a2 > m2) m2 = a2;
        if (a3 > m1) { m2 = m1; m1 = a3; } else if (a3 > m2) m2 = a3;
        flags[tok] = (m1 - m2 < GAP_TAU) ? 1 : 0;
    }
}

// ---------------------------------------------------------------- K4: full fp64 recompute (from raw x) of flagged tokens' logits
__global__ __launch_bounds__(256) void k4_recompute(const float* __restrict__ x,
                                                    const float* __restrict__ g,
                                                    const float* __restrict__ bvec,
                                                    const float* __restrict__ preW,
                                                    const float* __restrict__ preb,
                                                    const float* __restrict__ swW,
                                                    const float* __restrict__ swb,
                                                    const int* __restrict__ flags,
                                                    double* __restrict__ logitsD) {
    const int tok = blockIdx.x;
    if (!flags[tok]) return;
    __shared__ double xr[DIN];
    __shared__ double sw8[8];
    __shared__ double bcv[2];
    __shared__ double r4[4][4];
    const int tid = threadIdx.x, lane = tid & 63, wv = tid >> 6;

    double s = 0;
    for (int i = tid; i < DIN; i += 256) {
        const double v = (double)x[(size_t)tok * DIN + i];
        xr[i] = v;
        s += v;
    }
    s = waveRedD(s);
    if (lane == 0) sw8[wv] = s;
    __syncthreads();
    if (tid == 0) bcv[0] = (sw8[0] + sw8[1] + sw8[2] + sw8[3]) * (1.0 / 1024.0);
    __syncthreads();
    const double mu = bcv[0];
    double s2 = 0;
    for (int i = tid; i < DIN; i += 256) {
        const double d = xr[i] - mu;
        s2 += d * d;
    }
    s2 = waveRedD(s2);
    if (lane == 0) sw8[4 + wv] = s2;
    __syncthreads();
    if (tid == 0) bcv[1] = 1.0 / sqrt((sw8[4] + sw8[5] + sw8[6] + sw8[7]) * (1.0 / 1024.0) + 1e-5);
    __syncthreads();
    const double rs = bcv[1];
    for (int i = tid; i < DIN; i += 256)
        xr[i] = (xr[i] - mu) * rs * (double)g[i] + (double)bvec[i];
    __syncthreads();

    double l0 = 0, l1 = 0, l2 = 0, l3 = 0;
    for (int p = 0; p < 8; ++p) {
        const int c = p * 256 + tid;
        double z = (double)preb[c];
#pragma unroll 8
        for (int k = 0; k < DIN; ++k)
            z += xr[k] * (double)preW[(size_t)k * DMOD + c];
        const double t = gelud(z);
        const float4 wv4 = *(const float4*)&swW[(size_t)c * 4];
        l0 += t * (double)wv4.x; l1 += t * (double)wv4.y;
        l2 += t * (double)wv4.z; l3 += t * (double)wv4.w;
    }
    l0 = waveRedD(l0); l1 = waveRedD(l1); l2 = waveRedD(l2); l3 = waveRedD(l3);
    if (lane == 0) { r4[wv][0] = l0; r4[wv][1] = l1; r4[wv][2] = l2; r4[wv][3] = l3; }
    __syncthreads();
    if (tid == 0) {
#pragma unroll
        for (int e = 0; e < 4; ++e)
            logitsD[(size_t)tok * 4 + e] =
                r4[0][e] + r4[1][e] + r4[2][e] + r4[3][e] + (double)swb[e];
    }
}

// ---------------------------------------------------------------- K5: softmax + argmax + capacity scan (ballot-based)
__global__ __launch_bounds__(1024) void k5_scan(const double* __restrict__ logitsD,
                                                int* __restrict__ slot2tok,
                                                int* __restrict__ keepArr,
                                                int* __restrict__ keptcnt,
                                                float* __restrict__ outCounts,
                                                float* __restrict__ outPsum,
                                                float* __restrict__ outNdrop,
                                                float* __restrict__ outPmax) {
    __shared__ int wcnt[16][4];
    __shared__ unsigned int baseSh[4];
    __shared__ double redd[16];
    const int tid = threadIdx.x, lane = tid & 63, wv = tid >> 6;
    for (int i = tid; i < NEXP * CAPN; i += 1024) slot2tok[i] = 0;
    if (tid < 4) baseSh[tid] = 0;
    double p0 = 0, p1 = 0, p2 = 0, p3 = 0;
    __syncthreads();
    for (int c = 0; c < 9; ++c) {
        const int tok = c * 1024 + tid;
        const double* L = logitsD + (size_t)tok * 4;
        const double l0 = L[0], l1 = L[1], l2 = L[2], l3 = L[3];
        int r = 0;
        double m = l0;
        if (l1 > m) { m = l1; r = 1; }
        if (l2 > m) { m = l2; r = 2; }
        if (l3 > m) { m = l3; r = 3; }
        const double e0 = exp(l0 - m), e1 = exp(l1 - m), e2 = exp(l2 - m), e3 = exp(l3 - m);
        const double inv = 1.0 / (e0 + e1 + e2 + e3);
        p0 += e0 * inv; p1 += e1 * inv; p2 += e2 * inv; p3 += e3 * inv;
        outPmax[tok] = (float)inv;  // prob of argmax = exp(0)*inv
        const unsigned long long mm0 = __ballot(r == 0);
        const unsigned long long mm1 = __ballot(r == 1);
        const unsigned long long mm2 = __ballot(r == 2);
        const unsigned long long mm3 = __ballot(r == 3);
        const unsigned long long msel = (r == 0) ? mm0 : (r == 1) ? mm1 : (r == 2) ? mm2 : mm3;
        const unsigned long long below = (1ull << lane) - 1ull;
        const int posw = __popcll(msel & below);
        if (lane == 0) {
            wcnt[wv][0] = __popcll(mm0);
            wcnt[wv][1] = __popcll(mm1);
            wcnt[wv][2] = __popcll(mm2);
            wcnt[wv][3] = __popcll(mm3);
        }
        __syncthreads();
        int wbase = 0;
        for (int w2 = 0; w2 < wv; ++w2) wbase += wcnt[w2][r];
        const unsigned int pos = baseSh[r] + (unsigned int)(wbase + posw);
        const int kp = (pos < (unsigned int)CAPN) ? 1 : 0;
        keepArr[tok] = kp;
        if (kp) slot2tok[r * CAPN + pos] = tok;
        __syncthreads();
        if (tid < 4) {
            unsigned int tot = 0;
            for (int w2 = 0; w2 < 16; ++w2) tot += (unsigned int)wcnt[w2][tid];
            baseSh[tid] += tot;
        }
        __syncthreads();
    }
    if (tid < 4) {
        const unsigned int cnt = baseSh[tid];
        outCounts[tid] = (float)cnt;
        keptcnt[tid] = (cnt < (unsigned int)CAPN) ? (int)cnt : CAPN;
    }
    if (tid == 0) {
        int nd = 0;
#pragma unroll
        for (int e = 0; e < 4; ++e)
            nd += (baseSh[e] > (unsigned int)CAPN) ? (int)(baseSh[e] - CAPN) : 0;
        outNdrop[0] = (float)nd;
    }
    double pva[4] = {p0, p1, p2, p3};
#pragma unroll
    for (int e = 0; e < 4; ++e) {
        const double sr = waveRedD(pva[e]);
        __syncthreads();
        if (lane == 0) redd[wv] = sr;
        __syncthreads();
        if (tid == 0) {
            double tt = 0;
            for (int w2 = 0; w2 < 16; ++w2) tt += redd[w2];
            outPsum[e] = (float)tt;
        }
    }
}

// ---------------------------------------------------------------- K6: expert GEMM1 (fp16 MFMA, global_load_lds): h = gelu(X @ W1 + b1)
__global__ __launch_bounds__(256) void k6_ffn1(const half_t* __restrict__ t16,
                                               const half_t* __restrict__ w1t,  // [HDIM][DMOD]
                                               const float* __restrict__ b1e,
                                               const int* __restrict__ s2t,
                                               const int* __restrict__ keptp,
                                               half_t* __restrict__ hbuf) {
    const int kept = keptp[0];
    const int m0 = blockIdx.y * 128;
    if (m0 >= kept) return;
    const int n0 = blockIdx.x * 128;
    __shared__ half_t As[128 * 32];
    __shared__ half_t Bs[128 * 32];
    const int tid = threadIdx.x;
    const int r4 = tid >> 2, sg = (tid & 3) * 8;
    const int tok0 = s2t[m0 + r4];
    const int tok1 = s2t[m0 + 64 + r4];
    const half_t* gA0 = t16 + (size_t)tok0 * DMOD + sg;
    const half_t* gA1 = t16 + (size_t)tok1 * DMOD + sg;
    const half_t* gB0 = w1t + (size_t)(n0 + r4) * DMOD + sg;
    const half_t* gB1 = w1t + (size_t)(n0 + 64 + r4) * DMOD + sg;
    half_t* lA0 = &As[tid * 8]; half_t* lA1 = &As[2048 + tid * 8];
    half_t* lB0 = &Bs[tid * 8]; half_t* lB1 = &Bs[2048 + tid * 8];
    const int w = tid >> 6, lane = tid & 63, q = lane >> 4, mr = lane & 15;
    const int wm = (w & 1) * 64, wn = (w >> 1) * 64;

    f32x4 acc[4][4];
#pragma unroll
    for (int i = 0; i < 4; ++i)
#pragma unroll
        for (int j = 0; j < 4; ++j) acc[i][j] = (f32x4){0.f, 0.f, 0.f, 0.f};

    for (int k0 = 0; k0 < DMOD; k0 += 32) {
        gld16(gA0 + k0, lA0); gld16(gA1 + k0, lA1);
        gld16(gB0 + k0, lB0); gld16(gB1 + k0, lB1);
        __syncthreads();
        half8 afr[4], bfr[4];
#pragma unroll
        for (int i = 0; i < 4; ++i) {
            afr[i] = *(const half8*)&As[(wm + i * 16 + mr) * 32 + q * 8];
            bfr[i] = *(const half8*)&Bs[(wn + i * 16 + mr) * 32 + q * 8];
        }
#pragma unroll
        for (int i = 0; i < 4; ++i)
#pragma unroll
            for (int j = 0; j < 4; ++j)
                acc[i][j] = __builtin_amdgcn_mfma_f32_16x16x32_f16(afr[i], bfr[j], acc[i][j], 0, 0, 0);
        __syncthreads();
    }
    float bb[4];
#pragma unroll
    for (int j = 0; j < 4; ++j) bb[j] = b1e[n0 + wn + j * 16 + mr];
#pragma unroll
    for (int i = 0; i < 4; ++i) {
#pragma unroll
        for (int p = 0; p < 4; ++p) {
            const int row = m0 + wm + i * 16 + q * 4 + p;
            half_t* hp = hbuf + (size_t)row * HDIM;
#pragma unroll
            for (int j = 0; j < 4; ++j) {
                const int col = n0 + wn + j * 16 + mr;
                hp[col] = (half_t)geluf(acc[i][j][p] + bb[j]);
            }
        }
    }
}

// ---------------------------------------------------------------- K7: expert GEMM2 (fp16 MFMA, global_load_lds): final = (h @ W2 + b2) * pmax
__global__ __launch_bounds__(256) void k7_ffn2(const half_t* __restrict__ hbuf,
                                               const half_t* __restrict__ w2t,  // [DMOD][HDIM]
                                               const float* __restrict__ b2e,
                                               const int* __restrict__ s2t,
                                               const int* __restrict__ keptp,
                                               const float* __restrict__ pmax,
                                               float* __restrict__ outF) {
    const int kept = keptp[0];
    const int m0 = blockIdx.y * 128;
    if (m0 >= kept) return;
    const int n0 = blockIdx.x * 128;
    __shared__ half_t As[128 * 32];
    __shared__ half_t Bs[128 * 32];
    const int tid = threadIdx.x;
    const int r4 = tid >> 2, sg = (tid & 3) * 8;
    const half_t* gA0 = hbuf + (size_t)(m0 + r4) * HDIM + sg;
    const half_t* gA1 = hbuf + (size_t)(m0 + 64 + r4) * HDIM + sg;
    const half_t* gB0 = w2t + (size_t)(n0 + r4) * HDIM + sg;
    const half_t* gB1 = w2t + (size_t)(n0 + 64 + r4) * HDIM + sg;
    half_t* lA0 = &As[tid * 8]; half_t* lA1 = &As[2048 + tid * 8];
    half_t* lB0 = &Bs[tid * 8]; half_t* lB1 = &Bs[2048 + tid * 8];
    const int w = tid >> 6, lane = tid & 63, q = lane >> 4, mr = lane & 15;
    const int wm = (w & 1) * 64, wn = (w >> 1) * 64;

    f32x4 acc[4][4];
#pragma unroll
    for (int i = 0; i < 4; ++i)
#pragma unroll
        for (int j = 0; j < 4; ++j) acc[i][j] = (f32x4){0.f, 0.f, 0.f, 0.f};

    for (int k0 = 0; k0 < HDIM; k0 += 32) {
        gld16(gA0 + k0, lA0); gld16(gA1 + k0, lA1);
        gld16(gB0 + k0, lB0); gld16(gB1 + k0, lB1);
        __syncthreads();
        half8 afr[4], bfr[4];
#pragma unroll
        for (int i = 0; i < 4; ++i) {
            afr[i] = *(const half8*)&As[(wm + i * 16 + mr) * 32 + q * 8];
            bfr[i] = *(const half8*)&Bs[(wn + i * 16 + mr) * 32 + q * 8];
        }
#pragma unroll
        for (int i = 0; i < 4; ++i)
#pragma unroll
            for (int j = 0; j < 4; ++j)
                acc[i][j] = __builtin_amdgcn_mfma_f32_16x16x32_f16(afr[i], bfr[j], acc[i][j], 0, 0, 0);
        __syncthreads();
    }
    float bb[4];
#pragma unroll
    for (int j = 0; j < 4; ++j) bb[j] = b2e[n0 + wn + j * 16 + mr];
#pragma unroll
    for (int i = 0; i < 4; ++i) {
#pragma unroll
        for (int p = 0; p < 4; ++p) {
            const int gm = m0 + wm + i * 16 + q * 4 + p;
            if (gm < kept) {
                const int tok = s2t[gm];
                const float pm = pmax[tok];
                float* op = outF + (size_t)tok * DMOD;
#pragma unroll
                for (int j = 0; j < 4; ++j) {
                    const int col = n0 + wn + j * 16 + mr;
                    op[col] = (acc[i][j][p] + bb[j]) * pm;
                }
            }
        }
    }
}

// ---------------------------------------------------------------- K8: dropped-token passthrough
__global__ __launch_bounds__(256) void k8_pass(const int* __restrict__ keepArr,
                                               const float* __restrict__ t32,
                                               const float* __restrict__ pmax,
                                               float* __restrict__ outF) {
    const int tok = blockIdx.x;
    if (keepArr[tok]) return;
    const float pm = pmax[tok];
    const size_t base = (size_t)tok * DMOD;
    for (int c = threadIdx.x * 4; c < DMOD; c += 1024) {
        float4 v = *(const float4*)&t32[base + c];
        v.x *= pm; v.y *= pm; v.z *= pm; v.w *= pm;
        *(float4*)&outF[base + c] = v;
    }
}

// ---------------------------------------------------------------- launch
extern "C" void kernel_launch(void* const* d_in, const int* in_sizes, int n_in,
                              void* d_out, int out_size, void* d_ws, size_t ws_size,
                              hipStream_t stream) {
    const float* x     = (const float*)d_in[0];
    const float* ln_g  = (const float*)d_in[1];
    const float* ln_b  = (const float*)d_in[2];
    const float* pre_W = (const float*)d_in[3];
    const float* pre_b = (const float*)d_in[4];
    const float* sw_W  = (const float*)d_in[5];
    const float* sw_b  = (const float*)d_in[6];
    const float* W1    = (const float*)d_in[7];
    const float* b1    = (const float*)d_in[8];
    const float* W2    = (const float*)d_in[9];
    const float* b2    = (const float*)d_in[10];

    float* outF      = (float*)d_out;
    float* outCounts = outF + (size_t)T_TOK * DMOD;
    float* outPsum   = outCounts + 4;
    float* outNdrop  = outPsum + 4;
    float* outPmax   = outNdrop + 1;

    char* w = (char*)d_ws;
    const size_t OFF_XH  = 0;
    const size_t OFF_XL  = OFF_XH + (size_t)T_TOK * DIN * 2;
    const size_t OFF_WTH = OFF_XL + (size_t)T_TOK * DIN * 2;
    const size_t OFF_WTL = OFF_WTH + (size_t)DMOD * DIN * 2;
    const size_t OFF_T32 = OFF_WTL + (size_t)DMOD * DIN * 2;
    const size_t OFF_T16 = OFF_T32 + (size_t)T_TOK * DMOD * 4;
    const size_t OFF_H   = OFF_T16 + (size_t)T_TOK * DMOD * 2;
    const size_t OFF_WT  = OFF_H + (size_t)CAPN * HDIM * 2;
    const size_t OFF_LG  = OFF_WT + (size_t)HDIM * DMOD * 2;
    const size_t OFF_FL  = OFF_LG + (size_t)T_TOK * 4 * 8;
    const size_t OFF_KP  = OFF_FL + (size_t)T_TOK * 4;
    const size_t OFF_ST  = OFF_KP + (size_t)T_TOK * 4;
    const size_t OFF_KC  = OFF_ST + (size_t)NEXP * CAPN * 4;
    const size_t REQ     = OFF_KC + 256;
    if (ws_size < REQ) return;

    ushort_t* xh      = (ushort_t*)(w + OFF_XH);
    ushort_t* xl      = (ushort_t*)(w + OFF_XL);
    ushort_t* wth     = (ushort_t*)(w + OFF_WTH);
    ushort_t* wtl     = (ushort_t*)(w + OFF_WTL);
    float*    t32     = (float*)(w + OFF_T32);
    half_t*   t16     = (half_t*)(w + OFF_T16);
    half_t*   hbuf    = (half_t*)(w + OFF_H);
    half_t*   wT      = (half_t*)(w + OFF_WT);
    double*   logitsD = (double*)(w + OFF_LG);
    int*      flags   = (int*)(w + OFF_FL);
    int*      keepArr = (int*)(w + OFF_KP);
    int*      s2t     = (int*)(w + OFF_ST);
    int*      keptcnt = (int*)(w + OFF_KC);

    k1_ln<<<T_TOK, 256, 0, stream>>>(x, ln_g, ln_b, xh, xl);
    kt_bf16x2<<<dim3(DMOD / 64, DIN / 64), 256, 0, stream>>>(pre_W, wth, wtl, DIN, DMOD);
    k2_pre<<<dim3(DMOD / 128, T_TOK / 128), 256, 0, stream>>>(xh, xl, wth, wtl, pre_b, t32, t16);
    k3_router<<<T_TOK / 4, 256, 0, stream>>>(t32, sw_W, sw_b, logitsD, flags);
    k4_recompute<<<T_TOK, 256, 0, stream>>>(x, ln_g, ln_b, pre_W, pre_b, sw_W, sw_b,
                                            flags, logitsD);
    k5_scan<<<1, 1024, 0, stream>>>(logitsD, s2t, keepArr, keptcnt,
                                    outCounts, outPsum, outNdrop, outPmax);
    for (int e = 0; e < NEXP; ++e) {
        kt_f16<<<dim3(HDIM / 64, DMOD / 64), 256, 0, stream>>>(
            W1 + (size_t)e * DMOD * HDIM, wT, DMOD, HDIM);           // -> [HDIM][DMOD]
        k6_ffn1<<<dim3(HDIM / 128, CAPN / 128), 256, 0, stream>>>(
            t16, wT, b1 + (size_t)e * HDIM,
            s2t + (size_t)e * CAPN, keptcnt + e, hbuf);
        kt_f16<<<dim3(DMOD / 64, HDIM / 64), 256, 0, stream>>>(
            W2 + (size_t)e * HDIM * DMOD, wT, HDIM, DMOD);           // -> [DMOD][HDIM]
        k7_ffn2<<<dim3(DMOD / 128, CAPN / 128), 256, 0, stream>>>(
            hbuf, wT, b2 + (size_t)e * DMOD,
            s2t + (size_t)e * CAPN, keptcnt + e, outPmax, outF);
    }
    k8_pass<<<T_TOK, 256, 0, stream>>>(keepArr, t32, outPmax, outF);
}

// Round 2
// 2200.236 us; speedup vs baseline: 1.4729x; 1.0434x over previous
//
#include <hip/hip_runtime.h>
#include <cmath>

typedef _Float16 half_t;
typedef unsigned short ushort_t;
typedef __attribute__((ext_vector_type(8))) _Float16 half8;
typedef __attribute__((ext_vector_type(4))) _Float16 half4v;
typedef __attribute__((ext_vector_type(8))) short short8;
typedef __attribute__((ext_vector_type(4))) float f32x4;

#define T_TOK   9216
#define DIN     1024
#define DMOD    2048
#define HDIM    8192
#define NEXP    4
#define CAPN    3456          // int(1.5 * 9216 / 4)
#define GAP_TAU 5e-5          // top-2 gap below which we recompute logits in fp64
#define MAXF    64            // fast-path capacity for flagged tokens

__device__ inline float geluf(float x) {
    return 0.5f * x * (1.0f + erff(x * 0.70710678118654752440f));
}
__device__ inline double gelud(double x) {
    return 0.5 * x * (1.0 + erf(x * 0.70710678118654752440));
}
__device__ inline double waveRedD(double v) {
#pragma unroll
    for (int off = 32; off; off >>= 1) v += __shfl_down(v, off);
    return v;
}
__device__ inline ushort_t bf16rn(float f) {
    unsigned u = __float_as_uint(f);
    unsigned r = (u + 0x7FFFu + ((u >> 16) & 1u)) >> 16;
    return (ushort_t)r;
}
__device__ inline float bf16tof(ushort_t h) {
    return __uint_as_float(((unsigned)h) << 16);
}
// async global->LDS, 16 bytes/lane. LDS dest must be wave-uniform base + lane*16.
__device__ __forceinline__ void gld16(const void* g, void* l) {
    __builtin_amdgcn_global_load_lds((const __attribute__((address_space(1))) void*)g,
                                     (__attribute__((address_space(3))) void*)l, 16, 0, 0);
}

// ---------------------------------------------------------------- K1: LayerNorm (fp64 stats) -> bf16 hi/lo split
__global__ __launch_bounds__(256) void k1_ln(const float* __restrict__ x,
                                             const float* __restrict__ g,
                                             const float* __restrict__ b,
                                             ushort_t* __restrict__ xh,
                                             ushort_t* __restrict__ xl) {
    const int row = blockIdx.x;
    const int tid = threadIdx.x;
    const int c = tid * 4;
    const float4 v = *(const float4*)&x[(size_t)row * DIN + c];
    __shared__ double sw[8];
    __shared__ double bc[2];
    const int lane = tid & 63, wv = tid >> 6;

    double s = (double)v.x + (double)v.y + (double)v.z + (double)v.w;
    s = waveRedD(s);
    if (lane == 0) sw[wv] = s;
    __syncthreads();
    if (tid == 0) bc[0] = (sw[0] + sw[1] + sw[2] + sw[3]) * (1.0 / 1024.0);
    __syncthreads();
    const double mu = bc[0];
    const double d0 = (double)v.x - mu, d1 = (double)v.y - mu;
    const double d2 = (double)v.z - mu, d3 = (double)v.w - mu;
    double s2 = d0 * d0 + d1 * d1 + d2 * d2 + d3 * d3;
    s2 = waveRedD(s2);
    if (lane == 0) sw[4 + wv] = s2;
    __syncthreads();
    if (tid == 0) bc[1] = 1.0 / sqrt((sw[4] + sw[5] + sw[6] + sw[7]) * (1.0 / 1024.0) + 1e-5);
    __syncthreads();
    const double rs = bc[1];
    const float4 gv = *(const float4*)&g[c];
    const float4 bv = *(const float4*)&b[c];
    float o0 = (float)(d0 * rs * (double)gv.x + (double)bv.x);
    float o1 = (float)(d1 * rs * (double)gv.y + (double)bv.y);
    float o2 = (float)(d2 * rs * (double)gv.z + (double)bv.z);
    float o3 = (float)(d3 * rs * (double)gv.w + (double)bv.w);
    ushort4 hv, lv;
    hv.x = bf16rn(o0); lv.x = bf16rn(o0 - bf16tof(hv.x));
    hv.y = bf16rn(o1); lv.y = bf16rn(o1 - bf16tof(hv.y));
    hv.z = bf16rn(o2); lv.z = bf16rn(o2 - bf16tof(hv.z));
    hv.w = bf16rn(o3); lv.w = bf16rn(o3 - bf16tof(hv.w));
    *(ushort4*)&xh[(size_t)row * DIN + c] = hv;
    *(ushort4*)&xl[(size_t)row * DIN + c] = lv;
}

// ---------------------------------------------------------------- KT1: fp32 [K][N] -> bf16 hi/lo transposed [N][K]
#define TT_ST 68
__global__ __launch_bounds__(256) void kt_bf16x2(const float* __restrict__ src,
                                                 ushort_t* __restrict__ dhi,
                                                 ushort_t* __restrict__ dlo,
                                                 int K, int N) {
    __shared__ ushort_t th[64 * TT_ST];
    __shared__ ushort_t tl[64 * TT_ST];
    const int n0 = blockIdx.x * 64, k0 = blockIdx.y * 64;
    const int t = threadIdx.x, tr = t >> 4, tc = (t & 15) * 4;
#pragma unroll
    for (int r = 0; r < 4; ++r) {
        const int row = r * 16 + tr;
        const float4 v = *(const float4*)&src[(size_t)(k0 + row) * N + n0 + tc];
        const float vv[4] = {v.x, v.y, v.z, v.w};
#pragma unroll
        for (int j = 0; j < 4; ++j) {
            const ushort_t h = bf16rn(vv[j]);
            th[(tc + j) * TT_ST + row] = h;
            tl[(tc + j) * TT_ST + row] = bf16rn(vv[j] - bf16tof(h));
        }
    }
    __syncthreads();
#pragma unroll
    for (int r = 0; r < 4; ++r) {
        const int row = r * 16 + tr;
        ushort4 hv, lv;
        hv.x = th[row * TT_ST + tc + 0]; lv.x = tl[row * TT_ST + tc + 0];
        hv.y = th[row * TT_ST + tc + 1]; lv.y = tl[row * TT_ST + tc + 1];
        hv.z = th[row * TT_ST + tc + 2]; lv.z = tl[row * TT_ST + tc + 2];
        hv.w = th[row * TT_ST + tc + 3]; lv.w = tl[row * TT_ST + tc + 3];
        *(ushort4*)&dhi[(size_t)(n0 + row) * K + k0 + tc] = hv;
        *(ushort4*)&dlo[(size_t)(n0 + row) * K + k0 + tc] = lv;
    }
}

// ---------------------------------------------------------------- KT2: fp32 [K][N] -> fp16 transposed [N][K]
__global__ __launch_bounds__(256) void kt_f16(const float* __restrict__ src,
                                              half_t* __restrict__ dst,
                                              int K, int N) {
    __shared__ half_t tile[64 * TT_ST];
    const int n0 = blockIdx.x * 64, k0 = blockIdx.y * 64;
    const int t = threadIdx.x, tr = t >> 4, tc = (t & 15) * 4;
#pragma unroll
    for (int r = 0; r < 4; ++r) {
        const int row = r * 16 + tr;
        const float4 v = *(const float4*)&src[(size_t)(k0 + row) * N + n0 + tc];
        tile[(tc + 0) * TT_ST + row] = (half_t)v.x;
        tile[(tc + 1) * TT_ST + row] = (half_t)v.y;
        tile[(tc + 2) * TT_ST + row] = (half_t)v.z;
        tile[(tc + 3) * TT_ST + row] = (half_t)v.w;
    }
    __syncthreads();
#pragma unroll
    for (int r = 0; r < 4; ++r) {
        const int row = r * 16 + tr;
        const half4v v4 = *(const half4v*)&tile[row * TT_ST + tc];
        *(half4v*)&dst[(size_t)(n0 + row) * K + k0 + tc] = v4;
    }
}

// ---------------------------------------------------------------- K2: pre_linear bf16x3 MFMA GEMM + GELU
__global__ __launch_bounds__(256) void k2_pre(const ushort_t* __restrict__ xh,
                                              const ushort_t* __restrict__ xl,
                                              const ushort_t* __restrict__ wh,
                                              const ushort_t* __restrict__ wl,
                                              const float* __restrict__ bias,
                                              float* __restrict__ t32,
                                              half_t* __restrict__ t16) {
    __shared__ ushort_t Ah[128 * 32];
    __shared__ ushort_t Al[128 * 32];
    __shared__ ushort_t Bh[128 * 32];
    __shared__ ushort_t Bl[128 * 32];
    const int tid = threadIdx.x;
    // XCD-aware bijective swizzle (nwg = 16*72 = 1152, %8==0)
    int lin = blockIdx.y * gridDim.x + blockIdx.x;
    const int cpx = (gridDim.x * gridDim.y) >> 3;
    lin = (lin & 7) * cpx + (lin >> 3);
    const int m0 = (lin / gridDim.x) * 128, n0 = (lin % gridDim.x) * 128;
    const int r4 = tid >> 2, sg = (tid & 3) * 8;
    const ushort_t* gah0 = xh + (size_t)(m0 + r4) * DIN + sg;
    const ushort_t* gah1 = xh + (size_t)(m0 + 64 + r4) * DIN + sg;
    const ushort_t* gal0 = xl + (size_t)(m0 + r4) * DIN + sg;
    const ushort_t* gal1 = xl + (size_t)(m0 + 64 + r4) * DIN + sg;
    const ushort_t* gbh0 = wh + (size_t)(n0 + r4) * DIN + sg;
    const ushort_t* gbh1 = wh + (size_t)(n0 + 64 + r4) * DIN + sg;
    const ushort_t* gbl0 = wl + (size_t)(n0 + r4) * DIN + sg;
    const ushort_t* gbl1 = wl + (size_t)(n0 + 64 + r4) * DIN + sg;
    ushort_t* lAh0 = &Ah[tid * 8]; ushort_t* lAh1 = &Ah[2048 + tid * 8];
    ushort_t* lAl0 = &Al[tid * 8]; ushort_t* lAl1 = &Al[2048 + tid * 8];
    ushort_t* lBh0 = &Bh[tid * 8]; ushort_t* lBh1 = &Bh[2048 + tid * 8];
    ushort_t* lBl0 = &Bl[tid * 8]; ushort_t* lBl1 = &Bl[2048 + tid * 8];
    const int w = tid >> 6, lane = tid & 63, q = lane >> 4, mr = lane & 15;
    const int wm = (w & 1) * 64, wn = (w >> 1) * 64;

    f32x4 acc[4][4];
#pragma unroll
    for (int i = 0; i < 4; ++i)
#pragma unroll
        for (int j = 0; j < 4; ++j) acc[i][j] = (f32x4){0.f, 0.f, 0.f, 0.f};

    for (int k0 = 0; k0 < DIN; k0 += 32) {
        gld16(gah0 + k0, lAh0); gld16(gah1 + k0, lAh1);
        gld16(gal0 + k0, lAl0); gld16(gal1 + k0, lAl1);
        gld16(gbh0 + k0, lBh0); gld16(gbh1 + k0, lBh1);
        gld16(gbl0 + k0, lBl0); gld16(gbl1 + k0, lBl1);
        __syncthreads();
        short8 ah[4], al4[4], bh[4], bl4[4];
#pragma unroll
        for (int i = 0; i < 4; ++i) {
            ah[i]  = *(const short8*)&Ah[(wm + i * 16 + mr) * 32 + q * 8];
            al4[i] = *(const short8*)&Al[(wm + i * 16 + mr) * 32 + q * 8];
            bh[i]  = *(const short8*)&Bh[(wn + i * 16 + mr) * 32 + q * 8];
            bl4[i] = *(const short8*)&Bl[(wn + i * 16 + mr) * 32 + q * 8];
        }
#pragma unroll
        for (int i = 0; i < 4; ++i)
#pragma unroll
            for (int j = 0; j < 4; ++j) {
                acc[i][j] = __builtin_amdgcn_mfma_f32_16x16x32_bf16(al4[i], bh[j], acc[i][j], 0, 0, 0);
                acc[i][j] = __builtin_amdgcn_mfma_f32_16x16x32_bf16(ah[i], bl4[j], acc[i][j], 0, 0, 0);
                acc[i][j] = __builtin_amdgcn_mfma_f32_16x16x32_bf16(ah[i], bh[j], acc[i][j], 0, 0, 0);
            }
        __syncthreads();
    }
    float bb[4];
#pragma unroll
    for (int j = 0; j < 4; ++j) bb[j] = bias[n0 + wn + j * 16 + mr];
#pragma unroll
    for (int i = 0; i < 4; ++i) {
#pragma unroll
        for (int p = 0; p < 4; ++p) {
            const int row = m0 + wm + i * 16 + q * 4 + p;
#pragma unroll
            for (int j = 0; j < 4; ++j) {
                const int col = n0 + wn + j * 16 + mr;
                const float t = geluf(acc[i][j][p] + bb[j]);
                t32[(size_t)row * DMOD + col] = t;
                t16[(size_t)row * DMOD + col] = (half_t)t;
            }
        }
    }
}

// ---------------------------------------------------------------- K3: router logits (fp64) + gap flags + flagged-token compaction
__global__ __launch_bounds__(256) void k3_router(const float* __restrict__ t32,
                                                 const float* __restrict__ swW,
                                                 const float* __restrict__ swb,
                                                 double* __restrict__ logitsD,
                                                 int* __restrict__ flags,
                                                 int* __restrict__ flagidx,
                                                 int* __restrict__ fllist,
                                                 int* __restrict__ flcnt) {
    const int tok = blockIdx.x * 4 + (threadIdx.x >> 6);
    const int lane = threadIdx.x & 63;
    const float* tr = t32 + (size_t)tok * DMOD;
    double a0 = 0, a1 = 0, a2 = 0, a3 = 0;
    for (int it = 0; it < 8; ++it) {
        const int k = it * 256 + lane * 4;
        const float4 tv = *(const float4*)&tr[k];
        const float tp[4] = {tv.x, tv.y, tv.z, tv.w};
#pragma unroll
        for (int j = 0; j < 4; ++j) {
            const float4 wv = *(const float4*)&swW[(size_t)(k + j) * 4];
            const double td = (double)tp[j];
            a0 += td * (double)wv.x;
            a1 += td * (double)wv.y;
            a2 += td * (double)wv.z;
            a3 += td * (double)wv.w;
        }
    }
    a0 = waveRedD(a0); a1 = waveRedD(a1); a2 = waveRedD(a2); a3 = waveRedD(a3);
    if (lane == 0) {
        a0 += (double)swb[0]; a1 += (double)swb[1]; a2 += (double)swb[2]; a3 += (double)swb[3];
        double* Lp = logitsD + (size_t)tok * 4;
        Lp[0] = a0; Lp[1] = a1; Lp[2] = a2; Lp[3] = a3;
        double m1 = a0, m2 = -1e300;
        if (a1 > m1) { m2 = m1; m1 = a1; } else if (a1 > m2) m2 = a1;
        if (a2 > m1) { m2 = m1; m1 = a2; } else if (a2 > m2) m2 = a2;
        if (a3 > m1) { m2 = m1; m1 = a3; } else if (a3 > m2) m2 = a3;
        const int f = (m1 - m2 < GAP_TAU) ? 1 : 0;
        flags[tok] = f;
        if (f) {
            const int idx = atomicAdd(flcnt, 1);
            flagidx[tok] = idx;
            if (idx < MAXF) fllist[idx] = tok;
        }
    }
}

// ---------------------------------------------------------------- K4a: fp64 LN of flagged tokens -> xrbuf
__global__ __launch_bounds__(256) void k4a_xr(const float* __restrict__ x,
                                              const float* __restrict__ g,
                                              const float* __restrict__ bvec,
                                              const int* __restrict__ fllist,
                                              const int* __restrict__ flcnt,
                                              double* __restrict__ xrbuf) {
    const int bid = blockIdx.x;
    if (bid >= flcnt[0]) return;
    const int tok = fllist[bid];
    __shared__ double sw8[8];
    __shared__ double bcv[2];
    const int tid = threadIdx.x, lane = tid & 63, wv = tid >> 6;
    const int c = tid * 4;
    const float4 xv = *(const float4*)&x[(size_t)tok * DIN + c];
    const double d[4] = {(double)xv.x, (double)xv.y, (double)xv.z, (double)xv.w};
    double s = d[0] + d[1] + d[2] + d[3];
    s = waveRedD(s);
    if (lane == 0) sw8[wv] = s;
    __syncthreads();
    if (tid == 0) bcv[0] = (sw8[0] + sw8[1] + sw8[2] + sw8[3]) * (1.0 / 1024.0);
    __syncthreads();
    const double mu = bcv[0];
    double s2 = 0;
#pragma unroll
    for (int j = 0; j < 4; ++j) { const double dd = d[j] - mu; s2 += dd * dd; }
    s2 = waveRedD(s2);
    if (lane == 0) sw8[4 + wv] = s2;
    __syncthreads();
    if (tid == 0) bcv[1] = 1.0 / sqrt((sw8[4] + sw8[5] + sw8[6] + sw8[7]) * (1.0 / 1024.0) + 1e-5);
    __syncthreads();
    const double rs = bcv[1];
#pragma unroll
    for (int j = 0; j < 4; ++j)
        xrbuf[(size_t)bid * DIN + c + j] = (d[j] - mu) * rs * (double)g[c + j] + (double)bvec[c + j];
}

// ---------------------------------------------------------------- K4b: column-parallel fp64 dot for flagged tokens
__global__ __launch_bounds__(256) void k4b_dot(const double* __restrict__ xrbuf,
                                               const float* __restrict__ preW,
                                               const float* __restrict__ preb,
                                               const float* __restrict__ swW,
                                               const int* __restrict__ flcnt,
                                               double* __restrict__ part) {
    const int by = blockIdx.y;
    if (by >= flcnt[0]) return;
    const int tid = threadIdx.x;
    const int cl = tid & 31;
    const int col = blockIdx.x * 32 + cl;
    const int ks = tid >> 5;
    const double* xr = xrbuf + (size_t)by * DIN + ks * 128;
    const float* wp = preW + (size_t)(ks * 128) * DMOD + col;
    double z = 0;
#pragma unroll 4
    for (int k = 0; k < 128; ++k)
        z += xr[k] * (double)wp[(size_t)k * DMOD];
    __shared__ double red[32][9];
    red[cl][ks] = z;
    __syncthreads();
    if (tid < 32) {
        double s = (double)preb[col];
#pragma unroll
        for (int j = 0; j < 8; ++j) s += red[tid][j];
        const double t = gelud(s);
        const float4 wv4 = *(const float4*)&swW[(size_t)col * 4];
        double l0 = t * (double)wv4.x, l1 = t * (double)wv4.y;
        double l2 = t * (double)wv4.z, l3 = t * (double)wv4.w;
#pragma unroll
        for (int off = 16; off; off >>= 1) {
            l0 += __shfl_down(l0, off);
            l1 += __shfl_down(l1, off);
            l2 += __shfl_down(l2, off);
            l3 += __shfl_down(l3, off);
        }
        if (tid == 0) {
            double* pp = part + ((size_t)by * 64 + blockIdx.x) * 4;
            pp[0] = l0; pp[1] = l1; pp[2] = l2; pp[3] = l3;
        }
    }
}

// ---------------------------------------------------------------- K4c: fixed-order reduce of 64 partials -> logitsD
__global__ __launch_bounds__(64) void k4c_red(const double* __restrict__ part,
                                              const int* __restrict__ fllist,
                                              const int* __restrict__ flcnt,
                                              const float* __restrict__ swb,
                                              double* __restrict__ logitsD) {
    const int bid = blockIdx.x;
    if (bid >= flcnt[0]) return;
    const int tok = fllist[bid];
    const int lane = threadIdx.x;
#pragma unroll
    for (int e = 0; e < 4; ++e) {
        double v = part[((size_t)bid * 64 + lane) * 4 + e];
        v = waveRedD(v);
        if (lane == 0) logitsD[(size_t)tok * 4 + e] = v + (double)swb[e];
    }
}

// ---------------------------------------------------------------- K4d: fallback (only if >MAXF flagged; statistically never)
__global__ __launch_bounds__(256) void k4d_fallback(const float* __restrict__ x,
                                                    const float* __restrict__ g,
                                                    const float* __restrict__ bvec,
                                                    const float* __restrict__ preW,
                                                    const float* __restrict__ preb,
                                                    const float* __restrict__ swW,
                                                    const float* __restrict__ swb,
                                                    const int* __restrict__ flags,
                                                    const int* __restrict__ flagidx,
                                                    double* __restrict__ logitsD) {
    const int tok = blockIdx.x;
    if (!flags[tok]) return;
    if (flagidx[tok] < MAXF) return;
    __shared__ double xr[DIN];
    __shared__ double sw8[8];
    __shared__ double bcv[2];
    __shared__ double r4[4][4];
    const int tid = threadIdx.x, lane = tid & 63, wv = tid >> 6;

    double s = 0;
    for (int i = tid; i < DIN; i += 256) {
        const double v = (double)x[(size_t)tok * DIN + i];
        xr[i] = v;
        s += v;
    }
    s = waveRedD(s);
    if (lane == 0) sw8[wv] = s;
    __syncthreads();
    if (tid == 0) bcv[0] = (sw8[0] + sw8[1] + sw8[2] + sw8[3]) * (1.0 / 1024.0);
    __syncthreads();
    const double mu = bcv[0];
    double s2 = 0;
    for (int i = tid; i < DIN; i += 256) {
        const double d = xr[i] - mu;
        s2 += d * d;
    }
    s2 = waveRedD(s2);
    if (lane == 0) sw8[4 + wv] = s2;
    __syncthreads();
    if (tid == 0) bcv[1] = 1.0 / sqrt((sw8[4] + sw8[5] + sw8[6] + sw8[7]) * (1.0 / 1024.0) + 1e-5);
    __syncthreads();
    const double rs = bcv[1];
    for (int i = tid; i < DIN; i += 256)
        xr[i] = (xr[i] - mu) * rs * (double)g[i] + (double)bvec[i];
    __syncthreads();

    double l0 = 0, l1 = 0, l2 = 0, l3 = 0;
    for (int p = 0; p < 8; ++p) {
        const int c = p * 256 + tid;
        double z = (double)preb[c];
#pragma unroll 8
        for (int k = 0; k < DIN; ++k)
            z += xr[k] * (double)preW[(size_t)k * DMOD + c];
        const double t = gelud(z);
        const float4 wv4 = *(const float4*)&swW[(size_t)c * 4];
        l0 += t * (double)wv4.x; l1 += t * (double)wv4.y;
        l2 += t * (double)wv4.z; l3 += t * (double)wv4.w;
    }
    l0 = waveRedD(l0); l1 = waveRedD(l1); l2 = waveRedD(l2); l3 = waveRedD(l3);
    if (lane == 0) { r4[wv][0] = l0; r4[wv][1] = l1; r4[wv][2] = l2; r4[wv][3] = l3; }
    __syncthreads();
    if (tid == 0) {
#pragma unroll
        for (int e = 0; e < 4; ++e)
            logitsD[(size_t)tok * 4 + e] =
                r4[0][e] + r4[1][e] + r4[2][e] + r4[3][e] + (double)swb[e];
    }
}

// ---------------------------------------------------------------- K5: softmax + argmax + capacity scan (ballot-based)
__global__ __launch_bounds__(1024) void k5_scan(const double* __restrict__ logitsD,
                                                int* __restrict__ slot2tok,
                                                int* __restrict__ keepArr,
                                                int* __restrict__ keptcnt,
                                                float* __restrict__ outCounts,
                                                float* __restrict__ outPsum,
                                                float* __restrict__ outNdrop,
                                                float* __restrict__ outPmax) {
    __shared__ int wcnt[16][4];
    __shared__ unsigned int baseSh[4];
    __shared__ double redd[16];
    const int tid = threadIdx.x, lane = tid & 63, wv = tid >> 6;
    for (int i = tid; i < NEXP * CAPN; i += 1024) slot2tok[i] = 0;
    if (tid < 4) baseSh[tid] = 0;
    double p0 = 0, p1 = 0, p2 = 0, p3 = 0;
    __syncthreads();
    for (int c = 0; c < 9; ++c) {
        const int tok = c * 1024 + tid;
        const double* L = logitsD + (size_t)tok * 4;
        const double l0 = L[0], l1 = L[1], l2 = L[2], l3 = L[3];
        int r = 0;
        double m = l0;
        if (l1 > m) { m = l1; r = 1; }
        if (l2 > m) { m = l2; r = 2; }
        if (l3 > m) { m = l3; r = 3; }
        const double e0 = exp(l0 - m), e1 = exp(l1 - m), e2 = exp(l2 - m), e3 = exp(l3 - m);
        const double inv = 1.0 / (e0 + e1 + e2 + e3);
        p0 += e0 * inv; p1 += e1 * inv; p2 += e2 * inv; p3 += e3 * inv;
        outPmax[tok] = (float)inv;  // prob of argmax = exp(0)*inv
        const unsigned long long mm0 = __ballot(r == 0);
        const unsigned long long mm1 = __ballot(r == 1);
        const unsigned long long mm2 = __ballot(r == 2);
        const unsigned long long mm3 = __ballot(r == 3);
        const unsigned long long msel = (r == 0) ? mm0 : (r == 1) ? mm1 : (r == 2) ? mm2 : mm3;
        const unsigned long long below = (1ull << lane) - 1ull;
        const int posw = __popcll(msel & below);
        if (lane == 0) {
            wcnt[wv][0] = __popcll(mm0);
            wcnt[wv][1] = __popcll(mm1);
            wcnt[wv][2] = __popcll(mm2);
            wcnt[wv][3] = __popcll(mm3);
        }
        __syncthreads();
        int wbase = 0;
        for (int w2 = 0; w2 < wv; ++w2) wbase += wcnt[w2][r];
        const unsigned int pos = baseSh[r] + (unsigned int)(wbase + posw);
        const int kp = (pos < (unsigned int)CAPN) ? 1 : 0;
        keepArr[tok] = kp;
        if (kp) slot2tok[r * CAPN + pos] = tok;
        __syncthreads();
        if (tid < 4) {
            unsigned int tot = 0;
            for (int w2 = 0; w2 < 16; ++w2) tot += (unsigned int)wcnt[w2][tid];
            baseSh[tid] += tot;
        }
        __syncthreads();
    }
    if (tid < 4) {
        const unsigned int cnt = baseSh[tid];
        outCounts[tid] = (float)cnt;
        keptcnt[tid] = (cnt < (unsigned int)CAPN) ? (int)cnt : CAPN;
    }
    if (tid == 0) {
        int nd = 0;
#pragma unroll
        for (int e = 0; e < 4; ++e)
            nd += (baseSh[e] > (unsigned int)CAPN) ? (int)(baseSh[e] - CAPN) : 0;
        outNdrop[0] = (float)nd;
    }
    double pva[4] = {p0, p1, p2, p3};
#pragma unroll
    for (int e = 0; e < 4; ++e) {
        const double sr = waveRedD(pva[e]);
        __syncthreads();
        if (lane == 0) redd[wv] = sr;
        __syncthreads();
        if (tid == 0) {
            double tt = 0;
            for (int w2 = 0; w2 < 16; ++w2) tt += redd[w2];
            outPsum[e] = (float)tt;
        }
    }
}

// ---------------------------------------------------------------- K6: expert GEMM1 (fp16 MFMA, global_load_lds): h = gelu(X @ W1 + b1)
__global__ __launch_bounds__(256) void k6_ffn1(const half_t* __restrict__ t16,
                                               const half_t* __restrict__ w1t,  // [HDIM][DMOD]
                                               const float* __restrict__ b1e,
                                               const int* __restrict__ s2t,
                                               const int* __restrict__ keptp,
                                               half_t* __restrict__ hbuf) {
    const int kept = keptp[0];
    // XCD-aware bijective swizzle (nwg = 64*27 = 1728, %8==0)
    int lin = blockIdx.y * gridDim.x + blockIdx.x;
    const int cpx = (gridDim.x * gridDim.y) >> 3;
    lin = (lin & 7) * cpx + (lin >> 3);
    const int m0 = (lin / gridDim.x) * 128;
    if (m0 >= kept) return;
    const int n0 = (lin % gridDim.x) * 128;
    __shared__ half_t As[128 * 32];
    __shared__ half_t Bs[128 * 32];
    const int tid = threadIdx.x;
    const int r4 = tid >> 2, sg = (tid & 3) * 8;
    const int tok0 = s2t[m0 + r4];
    const int tok1 = s2t[m0 + 64 + r4];
    const half_t* gA0 = t16 + (size_t)tok0 * DMOD + sg;
    const half_t* gA1 = t16 + (size_t)tok1 * DMOD + sg;
    const half_t* gB0 = w1t + (size_t)(n0 + r4) * DMOD + sg;
    const half_t* gB1 = w1t + (size_t)(n0 + 64 + r4) * DMOD + sg;
    half_t* lA0 = &As[tid * 8]; half_t* lA1 = &As[2048 + tid * 8];
    half_t* lB0 = &Bs[tid * 8]; half_t* lB1 = &Bs[2048 + tid * 8];
    const int w = tid >> 6, lane = tid & 63, q = lane >> 4, mr = lane & 15;
    const int wm = (w & 1) * 64, wn = (w >> 1) * 64;

    f32x4 acc[4][4];
#pragma unroll
    for (int i = 0; i < 4; ++i)
#pragma unroll
        for (int j = 0; j < 4; ++j) acc[i][j] = (f32x4){0.f, 0.f, 0.f, 0.f};

    for (int k0 = 0; k0 < DMOD; k0 += 32) {
        gld16(gA0 + k0, lA0); gld16(gA1 + k0, lA1);
        gld16(gB0 + k0, lB0); gld16(gB1 + k0, lB1);
        __syncthreads();
        half8 afr[4], bfr[4];
#pragma unroll
        for (int i = 0; i < 4; ++i) {
            afr[i] = *(const half8*)&As[(wm + i * 16 + mr) * 32 + q * 8];
            bfr[i] = *(const half8*)&Bs[(wn + i * 16 + mr) * 32 + q * 8];
        }
#pragma unroll
        for (int i = 0; i < 4; ++i)
#pragma unroll
            for (int j = 0; j < 4; ++j)
                acc[i][j] = __builtin_amdgcn_mfma_f32_16x16x32_f16(afr[i], bfr[j], acc[i][j], 0, 0, 0);
        __syncthreads();
    }
    float bb[4];
#pragma unroll
    for (int j = 0; j < 4; ++j) bb[j] = b1e[n0 + wn + j * 16 + mr];
#pragma unroll
    for (int i = 0; i < 4; ++i) {
#pragma unroll
        for (int p = 0; p < 4; ++p) {
            const int row = m0 + wm + i * 16 + q * 4 + p;
            half_t* hp = hbuf + (size_t)row * HDIM;
#pragma unroll
            for (int j = 0; j < 4; ++j) {
                const int col = n0 + wn + j * 16 + mr;
                hp[col] = (half_t)geluf(acc[i][j][p] + bb[j]);
            }
        }
    }
}

// ---------------------------------------------------------------- K7: expert GEMM2 (fp16 MFMA, global_load_lds): final = (h @ W2 + b2) * pmax
__global__ __launch_bounds__(256) void k7_ffn2(const half_t* __restrict__ hbuf,
                                               const half_t* __restrict__ w2t,  // [DMOD][HDIM]
                                               const float* __restrict__ b2e,
                                               const int* __restrict__ s2t,
                                               const int* __restrict__ keptp,
                                               const float* __restrict__ pmax,
                                               float* __restrict__ outF) {
    const int kept = keptp[0];
    // XCD-aware bijective swizzle (nwg = 16*27 = 432, %8==0)
    int lin = blockIdx.y * gridDim.x + blockIdx.x;
    const int cpx = (gridDim.x * gridDim.y) >> 3;
    lin = (lin & 7) * cpx + (lin >> 3);
    const int m0 = (lin / gridDim.x) * 128;
    if (m0 >= kept) return;
    const int n0 = (lin % gridDim.x) * 128;
    __shared__ half_t As[128 * 32];
    __shared__ half_t Bs[128 * 32];
    const int tid = threadIdx.x;
    const int r4 = tid >> 2, sg = (tid & 3) * 8;
    const half_t* gA0 = hbuf + (size_t)(m0 + r4) * HDIM + sg;
    const half_t* gA1 = hbuf + (size_t)(m0 + 64 + r4) * HDIM + sg;
    const half_t* gB0 = w2t + (size_t)(n0 + r4) * HDIM + sg;
    const half_t* gB1 = w2t + (size_t)(n0 + 64 + r4) * HDIM + sg;
    half_t* lA0 = &As[tid * 8]; half_t* lA1 = &As[2048 + tid * 8];
    half_t* lB0 = &Bs[tid * 8]; half_t* lB1 = &Bs[2048 + tid * 8];
    const int w = tid >> 6, lane = tid & 63, q = lane >> 4, mr = lane & 15;
    const int wm = (w & 1) * 64, wn = (w >> 1) * 64;

    f32x4 acc[4][4];
#pragma unroll
    for (int i = 0; i < 4; ++i)
#pragma unroll
        for (int j = 0; j < 4; ++j) acc[i][j] = (f32x4){0.f, 0.f, 0.f, 0.f};

    for (int k0 = 0; k0 < HDIM; k0 += 32) {
        gld16(gA0 + k0, lA0); gld16(gA1 + k0, lA1);
        gld16(gB0 + k0, lB0); gld16(gB1 + k0, lB1);
        __syncthreads();
        half8 afr[4], bfr[4];
#pragma unroll
        for (int i = 0; i < 4; ++i) {
            afr[i] = *(const half8*)&As[(wm + i * 16 + mr) * 32 + q * 8];
            bfr[i] = *(const half8*)&Bs[(wn + i * 16 + mr) * 32 + q * 8];
        }
#pragma unroll
        for (int i = 0; i < 4; ++i)
#pragma unroll
            for (int j = 0; j < 4; ++j)
                acc[i][j] = __builtin_amdgcn_mfma_f32_16x16x32_f16(afr[i], bfr[j], acc[i][j], 0, 0, 0);
        __syncthreads();
    }
    float bb[4];
#pragma unroll
    for (int j = 0; j < 4; ++j) bb[j] = b2e[n0 + wn + j * 16 + mr];
#pragma unroll
    for (int i = 0; i < 4; ++i) {
#pragma unroll
        for (int p = 0; p < 4; ++p) {
            const int gm = m0 + wm + i * 16 + q * 4 + p;
            if (gm < kept) {
                const int tok = s2t[gm];
                const float pm = pmax[tok];
                float* op = outF + (size_t)tok * DMOD;
#pragma unroll
                for (int j = 0; j < 4; ++j) {
                    const int col = n0 + wn + j * 16 + mr;
                    op[col] = (acc[i][j][p] + bb[j]) * pm;
                }
            }
        }
    }
}

// ---------------------------------------------------------------- K8: dropped-token passthrough
__global__ __launch_bounds__(256) void k8_pass(const int* __restrict__ keepArr,
                                               const float* __restrict__ t32,
                                               const float* __restrict__ pmax,
                                               float* __restrict__ outF) {
    const int tok = blockIdx.x;
    if (keepArr[tok]) return;
    const float pm = pmax[tok];
    const size_t base = (size_t)tok * DMOD;
    for (int c = threadIdx.x * 4; c < DMOD; c += 1024) {
        float4 v = *(const float4*)&t32[base + c];
        v.x *= pm; v.y *= pm; v.z *= pm; v.w *= pm;
        *(float4*)&outF[base + c] = v;
    }
}

// ---------------------------------------------------------------- launch
extern "C" void kernel_launch(void* const* d_in, const int* in_sizes, int n_in,
                              void* d_out, int out_size, void* d_ws, size_t ws_size,
                              hipStream_t stream) {
    const float* x     = (const float*)d_in[0];
    const float* ln_g  = (const float*)d_in[1];
    const float* ln_b  = (const float*)d_in[2];
    const float* pre_W = (const float*)d_in[3];
    const float* pre_b = (const float*)d_in[4];
    const float* sw_W  = (const float*)d_in[5];
    const float* sw_b  = (const float*)d_in[6];
    const float* W1    = (const float*)d_in[7];
    const float* b1    = (const float*)d_in[8];
    const float* W2    = (const float*)d_in[9];
    const float* b2    = (const float*)d_in[10];

    float* outF      = (float*)d_out;
    float* outCounts = outF + (size_t)T_TOK * DMOD;
    float* outPsum   = outCounts + 4;
    float* outNdrop  = outPsum + 4;
    float* outPmax   = outNdrop + 1;

    char* w = (char*)d_ws;
    const size_t OFF_XH  = 0;
    const size_t OFF_XL  = OFF_XH + (size_t)T_TOK * DIN * 2;
    const size_t OFF_WTH = OFF_XL + (size_t)T_TOK * DIN * 2;
    const size_t OFF_WTL = OFF_WTH + (size_t)DMOD * DIN * 2;
    const size_t OFF_T32 = OFF_WTL + (size_t)DMOD * DIN * 2;
    const size_t OFF_T16 = OFF_T32 + (size_t)T_TOK * DMOD * 4;
    const size_t OFF_H   = OFF_T16 + (size_t)T_TOK * DMOD * 2;
    const size_t OFF_WT  = OFF_H + (size_t)CAPN * HDIM * 2;
    const size_t OFF_LG  = OFF_WT + (size_t)HDIM * DMOD * 2;
    const size_t OFF_FL  = OFF_LG + (size_t)T_TOK * 4 * 8;
    const size_t OFF_KP  = OFF_FL + (size_t)T_TOK * 4;
    const size_t OFF_ST  = OFF_KP + (size_t)T_TOK * 4;
    const size_t OFF_KC  = OFF_ST + (size_t)NEXP * CAPN * 4;
    const size_t OFF_FLL = OFF_KC + 256;
    const size_t OFF_FID = OFF_FLL + (size_t)MAXF * 4;
    const size_t OFF_CNT = OFF_FID + (size_t)T_TOK * 4;
    const size_t OFF_XR  = OFF_CNT + 256;
    const size_t OFF_PRT = OFF_XR + (size_t)MAXF * DIN * 8;
    const size_t REQ     = OFF_PRT + (size_t)MAXF * 64 * 4 * 8;
    if (ws_size < REQ) return;

    ushort_t* xh      = (ushort_t*)(w + OFF_XH);
    ushort_t* xl      = (ushort_t*)(w + OFF_XL);
    ushort_t* wth     = (ushort_t*)(w + OFF_WTH);
    ushort_t* wtl     = (ushort_t*)(w + OFF_WTL);
    float*    t32     = (float*)(w + OFF_T32);
    half_t*   t16     = (half_t*)(w + OFF_T16);
    half_t*   hbuf    = (half_t*)(w + OFF_H);
    half_t*   wT      = (half_t*)(w + OFF_WT);
    double*   logitsD = (double*)(w + OFF_LG);
    int*      flags   = (int*)(w + OFF_FL);
    int*      keepArr = (int*)(w + OFF_KP);
    int*      s2t     = (int*)(w + OFF_ST);
    int*      keptcnt = (int*)(w + OFF_KC);
    int*      fllist  = (int*)(w + OFF_FLL);
    int*      flagidx = (int*)(w + OFF_FID);
    int*      flcnt   = (int*)(w + OFF_CNT);
    double*   xrbuf   = (double*)(w + OFF_XR);
    double*   part    = (double*)(w + OFF_PRT);

    k1_ln<<<T_TOK, 256, 0, stream>>>(x, ln_g, ln_b, xh, xl);
    kt_bf16x2<<<dim3(DMOD / 64, DIN / 64), 256, 0, stream>>>(pre_W, wth, wtl, DIN, DMOD);
    k2_pre<<<dim3(DMOD / 128, T_TOK / 128), 256, 0, stream>>>(xh, xl, wth, wtl, pre_b, t32, t16);
    hipMemsetAsync(flcnt, 0, sizeof(int), stream);
    k3_router<<<T_TOK / 4, 256, 0, stream>>>(t32, sw_W, sw_b, logitsD, flags,
                                             flagidx, fllist, flcnt);
    k4a_xr<<<MAXF, 256, 0, stream>>>(x, ln_g, ln_b, fllist, flcnt, xrbuf);
    k4b_dot<<<dim3(64, MAXF), 256, 0, stream>>>(xrbuf, pre_W, pre_b, sw_W, flcnt, part);
    k4c_red<<<MAXF, 64, 0, stream>>>(part, fllist, flcnt, sw_b, logitsD);
    k4d_fallback<<<T_TOK, 256, 0, stream>>>(x, ln_g, ln_b, pre_W, pre_b, sw_W, sw_b,
                                            flags, flagidx, logitsD);
    k5_scan<<<1, 1024, 0, stream>>>(logitsD, s2t, keepArr, keptcnt,
                                    outCounts, outPsum, outNdrop, outPmax);
    for (int e = 0; e < NEXP; ++e) {
        kt_f16<<<dim3(HDIM / 64, DMOD / 64), 256, 0, stream>>>(
            W1 + (size_t)e * DMOD * HDIM, wT, DMOD, HDIM);           // -> [HDIM][DMOD]
        k6_ffn1<<<dim3(HDIM / 128, CAPN / 128), 256, 0, stream>>>(
            t16, wT, b1 + (size_t)e * HDIM,
            s2t + (size_t)e * CAPN, keptcnt + e, hbuf);
        kt_f16<<<dim3(DMOD / 64, HDIM / 64), 256, 0, stream>>>(
            W2 + (size_t)e * HDIM * DMOD, wT, HDIM, DMOD);           // -> [DMOD][HDIM]
        k7_ffn2<<<dim3(DMOD / 128, CAPN / 128), 256, 0, stream>>>(
            hbuf, wT, b2 + (size_t)e * DMOD,
            s2t + (size_t)e * CAPN, keptcnt + e, outPmax, outF);
    }
    k8_pass<<<T_TOK, 256, 0, stream>>>(keepArr, t32, outPmax, outF);
}